// Round 3
// baseline (193.234 us; speedup 1.0000x reference)
//
#include <hip/hip_runtime.h>

// ManifoldAttentionLayer on MI355X — round 11
// R10 post-mortem: halving LDS reads AND occupancy left flash at 43.8us
// (R8 44.2) -> LDS BW and TLP both ruled out. Invariant across R8/R10: the
// per-iteration __syncthreads forces s_waitcnt vmcnt(0) (compiler drains the
// same-iteration prefetch DMAs) and phase-aligns all waves (QK | softmax | PV
// alternate, pipes idle in turn) — the m97 2-barrier-per-K-step ceiling.
// R11 (T3/T4): 3 LDS buffers, DMA issued 2 tiles ahead, iteration boundary =
// inline-asm s_waitcnt vmcnt(6) + raw s_barrier (loads stay in flight across
// barriers, never drain to 0 mid-loop). Plus: l_part was a 32-deep serial
// dependent-add chain per iter -> float4 accumulator (depth 4), lane-reduce in
// epilogue. LDS 48->72 KB, still 2 blocks/CU.

using short8  = __attribute__((ext_vector_type(8))) short;
using short4v = __attribute__((ext_vector_type(4))) short;
using float4v = __attribute__((ext_vector_type(4))) float;

#define MFMA16(a, b, c) __builtin_amdgcn_mfma_f32_16x16x32_bf16((a), (b), (c), 0, 0, 0)

#define LOG2E 1.44269504088896f

static __device__ __forceinline__ short f2bf(float f) {
    union { float f; unsigned u; } v; v.f = f;
    unsigned r = v.u + 0x7fffu + ((v.u >> 16) & 1u);   // round-to-nearest-even
    return (short)(r >> 16);
}

// pack two f32 -> packed bf16 pair (round-half-up): 2 adds + 1 v_perm. PROVEN R5-R10.
static __device__ __forceinline__ unsigned pack2bf(float lo, float hi) {
    union { float f; unsigned u; } a, b;
    a.f = lo; b.f = hi;
    return __builtin_amdgcn_perm(b.u + 0x8000u, a.u + 0x8000u, 0x07060302u);
}

// async global->LDS DMA, 16B/lane; LDS dest = wave-uniform base + lane*16.
static __device__ __forceinline__ void dma16(const short* g, short* l) {
    __builtin_amdgcn_global_load_lds((const __attribute__((address_space(1))) void*)g,
                                     (__attribute__((address_space(3))) void*)l, 16, 0, 0);
}

// ---------------- 1) fp32 -> bf16: x and the 4 weight matrices ----------------
__global__ __launch_bounds__(256) void convert_all(
    const float* __restrict__ x,  const float* __restrict__ wq,
    const float* __restrict__ wk, const float* __restrict__ wv,
    const float* __restrict__ wo, short* __restrict__ xb, short* __restrict__ wb) {
    int idx = blockIdx.x * 256 + threadIdx.x;
    for (int i = idx; i < 2097152; i += gridDim.x * 256) {
        const float* src; short* dst;
        if (i < 1048576) {
            src = x + (size_t)i * 4;
            dst = xb + (size_t)i * 4;
        } else {
            int j = i - 1048576;
            int sel = j >> 18;
            const float* w = (sel == 0) ? wq : (sel == 1) ? wk : (sel == 2) ? wv : wo;
            src = w + (size_t)(j & 262143) * 4;
            dst = wb + (size_t)j * 4;
        }
        float4v v = *(const float4v*)src;
        short4v o;
        o.x = f2bf(v.x); o.y = f2bf(v.y); o.z = f2bf(v.z); o.w = f2bf(v.w);
        *(short4v*)dst = o;
    }
}

// ---------------- 2+4) fill augmented dims of Q'/K' (gram inline) ----------------
__global__ __launch_bounds__(256) void fill_aug(const float* __restrict__ harm,
                                                short* __restrict__ Qp,
                                                short* __restrict__ Kp) {
    int b  = blockIdx.y;
    int lc = blockIdx.x;
    int tid = threadIdx.x;
    int ll = tid >> 3;
    int d8 = (tid & 7) * 8;
    int l  = lc * 32 + ll;

    __shared__ float hs[64][33];
    for (int i = tid; i < 2048; i += 256) hs[i >> 5][i & 31] = harm[(size_t)b * 2048 + i];
    __syncthreads();

    float src = (l + 0.5f) * 0.0625f - 0.5f;
    if (src < 0.f) src = 0.f;
    int r0 = (int)floorf(src); if (r0 > 63) r0 = 63;
    int r1 = r0 + 1;           if (r1 > 63) r1 = 63;
    float wy = src - (float)r0;

    float hr[32];
    #pragma unroll
    for (int k = 0; k < 32; k++) hr[k] = (1.f - wy) * hs[r0][k] + wy * hs[r1][k];

    short8 qa, ka;
    #pragma unroll
    for (int j = 0; j < 8; j++) {
        float g = 0.f;
        #pragma unroll
        for (int k = 0; k < 32; k++) g += hr[k] * hs[d8 + j][k];
        qa[j] = f2bf(0.1f * LOG2E * g);
    }
    #pragma unroll
    for (int j = 0; j < 8; j++) {
        float vv = 0.f;
        if (d8 + j == r0) vv += 1.f - wy;
        if (d8 + j == r1) vv += wy;
        ka[j] = f2bf(vv);
    }
    for (int h = 0; h < 16; h++) {
        size_t base = (((size_t)(b * 16 + h) * 1024 + l) << 7) + 64 + d8;
        *(short8*)(Qp + base) = qa;
        *(short8*)(Kp + base) = ka;
    }
}

// ---------------- 3/6) GEMM (R7 structure, unchanged) ----------------
template <int MODE>
__global__ __launch_bounds__(256, 2) void gemm_kernel(
    const short* __restrict__ A,
    const short* __restrict__ Wb,
    const float* __restrict__ B0, const float* __restrict__ B1, const float* __restrict__ B2,
    short* __restrict__ Qp, short* __restrict__ Kp, short* __restrict__ Vp,
    float* __restrict__ outF) {
    const int z = blockIdx.z;
    const short* W  = Wb + (size_t)z * 1048576;
    const float* Bs = (z == 0) ? B0 : ((z == 1) ? B1 : B2);

    __shared__ short Sm[2][8192];   // [buf][A 0..4096 | W 4096..8192], 32 KB

    const int tid  = threadIdx.x;
    const int lane = tid & 63;
    const int wv   = tid >> 6;
    const int wm   = (wv >> 1) * 64;
    const int wn   = (wv & 1) * 64;
    const int l16  = lane & 15;
    const int quad = lane >> 4;
    const int bm   = blockIdx.x * 128;
    const int bn   = blockIdx.y * 128;

    const short* aSrc[2];
    const short* wSrc[2];
    #pragma unroll
    for (int j = 0; j < 2; j++) {
        int c = j * 256 + tid;
        int r = c >> 2, gs = (c & 3) ^ ((r >> 1) & 3);
        aSrc[j] = A + (size_t)(bm + r) * 1024 + gs * 8;
        wSrc[j] = W + (size_t)(bn + r) * 1024 + gs * 8;
    }
    const int fr = (quad ^ ((l16 >> 1) & 3)) * 8;
    int ai[4], bi[4];
    #pragma unroll
    for (int t = 0; t < 4; t++) {
        ai[t] = (wm + t * 16 + l16) * 32 + fr;
        bi[t] = 4096 + (wn + t * 16 + l16) * 32 + fr;
    }

    float4v zero4 = {0.f, 0.f, 0.f, 0.f};
    float4v acc[4][4];
    #pragma unroll
    for (int i = 0; i < 4; i++)
        #pragma unroll
        for (int j = 0; j < 4; j++) acc[i][j] = zero4;

    dma16(aSrc[0], &Sm[0][wv * 512]);
    dma16(aSrc[1], &Sm[0][2048 + wv * 512]);
    dma16(wSrc[0], &Sm[0][4096 + wv * 512]);
    dma16(wSrc[1], &Sm[0][6144 + wv * 512]);
    #pragma unroll
    for (int j = 0; j < 2; j++) { aSrc[j] += 32; wSrc[j] += 32; }
    __syncthreads();

    for (int kt = 0; kt < 32; kt++) {
        const int cur = kt & 1, nxt = cur ^ 1;
        if (kt < 31) {
            dma16(aSrc[0], &Sm[nxt][wv * 512]);
            dma16(aSrc[1], &Sm[nxt][2048 + wv * 512]);
            dma16(wSrc[0], &Sm[nxt][4096 + wv * 512]);
            dma16(wSrc[1], &Sm[nxt][6144 + wv * 512]);
            #pragma unroll
            for (int j = 0; j < 2; j++) { aSrc[j] += 32; wSrc[j] += 32; }
        }

        short8 af[4], bfr[4];
        #pragma unroll
        for (int mt = 0; mt < 4; mt++) af[mt]  = *(const short8*)&Sm[cur][ai[mt]];
        #pragma unroll
        for (int nt = 0; nt < 4; nt++) bfr[nt] = *(const short8*)&Sm[cur][bi[nt]];
        #pragma unroll
        for (int mt = 0; mt < 4; mt++)
            #pragma unroll
            for (int nt = 0; nt < 4; nt++)
                acc[mt][nt] = MFMA16(af[mt], bfr[nt], acc[mt][nt]);

        __syncthreads();
    }

    #pragma unroll
    for (int mt = 0; mt < 4; mt++)
        #pragma unroll
        for (int nt = 0; nt < 4; nt++) {
            int col = bn + wn + nt * 16 + l16;
            float bias = Bs[col];
            #pragma unroll
            for (int r = 0; r < 4; r++) {
                int row = bm + wm + mt * 16 + quad * 4 + r;
                float val = acc[mt][nt][r] + bias;
                if (MODE == 1) {
                    outF[(size_t)row * 1024 + col] = val;
                } else {
                    int b = row >> 10, l = row & 1023;
                    int h = col >> 6,  d = col & 63;
                    size_t bhl = (size_t)(b * 16 + h) * 1024 + l;
                    if (z == 0)      Qp[(bhl << 7) + d] = f2bf(val * (0.125f * LOG2E));
                    else if (z == 1) Kp[(bhl << 7) + d] = f2bf(val);
                    else {
                        int slot = (l & ~31) | (((l >> 2) & 3) << 3) |
                                   (((l >> 4) & 1) << 2) | (l & 3);
                        Vp[(((size_t)(b * 16 + h) * 64 + d) << 10) + slot] = f2bf(val);
                    }
                }
            }
        }
}

// ---------------- 5) flash attention: 256 thr, 4 waves x 32 q, 3-buf pipeline ----
// R11: DMA issued 2 tiles ahead into a 3-deep ring; iteration boundary is
// s_waitcnt vmcnt(6) + raw s_barrier (T4 counted wait — the 6 newest DMAs, for
// tile kt+2, stay in flight across the barrier). Buffer (kt+2)%3 was last read
// in iteration kt-1, two barriers before rewrite -> no race.
__global__ __launch_bounds__(256, 2)
void flash_kernel(const short* __restrict__ Qp,
                  const short* __restrict__ Kp,
                  const short* __restrict__ Vp,
                  short* __restrict__ AO) {
    const int h  = blockIdx.x;
    const int qb = blockIdx.y;
    const int b  = blockIdx.z;
    const int tid  = threadIdx.x;
    const int lane = tid & 63;
    const int w    = tid >> 6;          // wave 0..3, owns 32 q rows
    const int l16  = lane & 15;
    const int quad = lane >> 4;
    const size_t bh = (size_t)(b * 16 + h);

    __shared__ short Ks[24576];   // 3 x 8192 shorts (64 key x 128 d)
    __shared__ short Vs[12288];   // 3 x 4096 shorts (64 d x 64 slot)

    // Q fragments (B-operand): u-half, lane l16 -> q row w*32+u*16+l16, k = c*32+quad*8+j
    short8 qf[2][4];
    #pragma unroll
    for (int u = 0; u < 2; u++) {
        const short* Qb = Qp + ((bh * 1024 + qb * 128 + w * 32 + u * 16 + l16) << 7) + quad * 8;
        #pragma unroll
        for (int c = 0; c < 4; c++) qf[u][c] = *(const short8*)(Qb + c * 32);
    }

    // staging sources (source-side swizzle, lane-linear LDS); wave w owns
    // keys/d-rows w*16 .. w*16+15
    const short* kSrc[4];
    #pragma unroll
    for (int jj = 0; jj < 4; jj++) {
        int key = w * 16 + jj * 4 + quad;
        kSrc[jj] = Kp + (bh << 17) + key * 128 + ((l16 ^ (key & 15)) * 8);
    }
    const short* vSrc[2];
    #pragma unroll
    for (int g = 0; g < 2; g++) {
        int d = w * 16 + g * 8 + (lane >> 3);
        vSrc[g] = Vp + (bh << 16) + d * 1024 + (((lane & 7) ^ (d & 7)) * 8);
    }

    int krd[4];
    #pragma unroll
    for (int c = 0; c < 4; c++) krd[c] = l16 * 128 + (((c * 4 + quad) ^ l16) * 8);
    int vrd[2];
    #pragma unroll
    for (int g = 0; g < 2; g++) vrd[g] = l16 * 64 + (((g * 4 + quad) ^ (l16 & 7)) * 8);

    // prologue: T0 -> buf0, T1 -> buf1 (12 DMAs/wave outstanding), then wait
    // for T0 only (vmcnt(6): in-order retirement, 6 oldest = T0's).
    #pragma unroll
    for (int jj = 0; jj < 4; jj++) dma16(kSrc[jj], &Ks[w * 2048 + jj * 512]);
    #pragma unroll
    for (int g = 0; g < 2; g++) dma16(vSrc[g], &Vs[w * 1024 + g * 512]);
    #pragma unroll
    for (int jj = 0; jj < 4; jj++) kSrc[jj] += 8192;
    #pragma unroll
    for (int g = 0; g < 2; g++) vSrc[g] += 64;
    #pragma unroll
    for (int jj = 0; jj < 4; jj++) dma16(kSrc[jj], &Ks[8192 + w * 2048 + jj * 512]);
    #pragma unroll
    for (int g = 0; g < 2; g++) dma16(vSrc[g], &Vs[4096 + w * 1024 + g * 512]);
    #pragma unroll
    for (int jj = 0; jj < 4; jj++) kSrc[jj] += 8192;
    #pragma unroll
    for (int g = 0; g < 2; g++) vSrc[g] += 64;

    float4v zero4 = {0.f, 0.f, 0.f, 0.f};
    float4v o_acc[2][4];
    #pragma unroll
    for (int u = 0; u < 2; u++)
        #pragma unroll
        for (int mt = 0; mt < 4; mt++) o_acc[u][mt] = zero4;
    float4v l_acc[2] = {zero4, zero4};

    asm volatile("s_waitcnt vmcnt(6)" ::: "memory");
    __builtin_amdgcn_s_barrier();
    __builtin_amdgcn_sched_barrier(0);

    int bufR = 0;   // read buffer for tile kt
    int bufW = 2;   // write buffer for tile kt+2

    for (int kt = 0; kt < 16; kt++) {
        if (kt < 14) {
            const int wb = bufW << 13;   // K base (shorts)
            const int wv2 = bufW << 12;  // V base
            #pragma unroll
            for (int jj = 0; jj < 4; jj++) dma16(kSrc[jj], &Ks[wb + w * 2048 + jj * 512]);
            #pragma unroll
            for (int g = 0; g < 2; g++) dma16(vSrc[g], &Vs[wv2 + w * 1024 + g * 512]);
            #pragma unroll
            for (int jj = 0; jj < 4; jj++) kSrc[jj] += 8192;
            #pragma unroll
            for (int g = 0; g < 2; g++) vSrc[g] += 64;
        }
        const int kb = bufR << 13;
        const int vb = bufR << 12;

        // S^T = K·Q^T (C-layout: col=l16=q, row=key=mt*16+quad*4+r); kf shared by u=0,1
        float4v s[2][4];
        #pragma unroll
        for (int mt = 0; mt < 4; mt++) {
            short8 kf[4];
            #pragma unroll
            for (int c = 0; c < 4; c++) kf[c] = *(const short8*)&Ks[kb + krd[c] + mt * 2048];
            #pragma unroll
            for (int u = 0; u < 2; u++) {
                s[u][mt] = MFMA16(kf[0], qf[u][0], zero4);
                #pragma unroll
                for (int c = 1; c < 4; c++)
                    s[u][mt] = MFMA16(kf[c], qf[u][c], s[u][mt]);
            }
        }

        // p = exp2(s); l accumulates as float4 (chain depth 4, not 32)
        #pragma unroll
        for (int u = 0; u < 2; u++)
            #pragma unroll
            for (int mt = 0; mt < 4; mt++) {
                #pragma unroll
                for (int r = 0; r < 4; r++)
                    s[u][mt][r] = __builtin_exp2f(s[u][mt][r]);
                #pragma unroll
                for (int r = 0; r < 4; r++)
                    l_acc[u][r] += s[u][mt][r];
            }

        // O^T += V^T · P^T; vf shared by u=0,1
        #pragma unroll
        for (int g = 0; g < 2; g++) {
            short8 pf[2];
            #pragma unroll
            for (int u = 0; u < 2; u++) {
                union { unsigned uu[4]; short8 v; } t;
                t.uu[0] = pack2bf(s[u][2 * g][0], s[u][2 * g][1]);
                t.uu[1] = pack2bf(s[u][2 * g][2], s[u][2 * g][3]);
                t.uu[2] = pack2bf(s[u][2 * g + 1][0], s[u][2 * g + 1][1]);
                t.uu[3] = pack2bf(s[u][2 * g + 1][2], s[u][2 * g + 1][3]);
                pf[u] = t.v;
            }
            #pragma unroll
            for (int mt = 0; mt < 4; mt++) {
                short8 vf = *(const short8*)&Vs[vb + vrd[g] + mt * 1024];
                #pragma unroll
                for (int u = 0; u < 2; u++)
                    o_acc[u][mt] = MFMA16(vf, pf[u], o_acc[u][mt]);
            }
        }

        // iteration boundary: wait only for tile kt+1 (leave kt+2's 6 in flight)
        if (kt < 15) {
            if (kt < 14) {
                asm volatile("s_waitcnt vmcnt(6)" ::: "memory");
            } else {
                asm volatile("s_waitcnt vmcnt(0)" ::: "memory");
            }
            __builtin_amdgcn_s_barrier();
            __builtin_amdgcn_sched_barrier(0);
        }
        bufR = (bufR >= 2) ? 0 : bufR + 1;
        bufW = (bufW >= 2) ? 0 : bufW + 1;
    }

    // epilogue: reduce l lanes + quads, normalize, store (per q-half)
    #pragma unroll
    for (int u = 0; u < 2; u++) {
        float l = l_acc[u][0] + l_acc[u][1] + l_acc[u][2] + l_acc[u][3];
        l += __shfl_xor(l, 16, 64);
        l += __shfl_xor(l, 32, 64);
        float inv = 1.0f / l;
        int row = b * 1024 + qb * 128 + w * 32 + u * 16 + l16;
        #pragma unroll
        for (int mt = 0; mt < 4; mt++) {
            short4v ov;
            #pragma unroll
            for (int r = 0; r < 4; r++) ov[r] = f2bf(o_acc[u][mt][r] * inv);
            *(short4v*)(AO + (size_t)row * 1024 + h * 64 + mt * 16 + quad * 4) = ov;
        }
    }
}

extern "C" void kernel_launch(void* const* d_in, const int* in_sizes, int n_in,
                              void* d_out, int out_size, void* d_ws, size_t ws_size,
                              hipStream_t stream) {
    const float* x    = (const float*)d_in[0];
    const float* harm = (const float*)d_in[1];
    const float* wq   = (const float*)d_in[2];
    const float* bq   = (const float*)d_in[3];
    const float* wk   = (const float*)d_in[4];
    const float* bk   = (const float*)d_in[5];
    const float* wv   = (const float*)d_in[6];
    const float* bv   = (const float*)d_in[7];
    const float* wo   = (const float*)d_in[8];
    const float* bo   = (const float*)d_in[9];
    float* outF = (float*)d_out;

    short* xb   = (short*)d_ws;                 // 4M shorts; ALIASED as AO
    short* Qp   = xb + (size_t)4 * 1048576;     // 8M shorts
    short* Kp   = Qp + (size_t)8 * 1048576;     // 8M shorts
    short* Vp   = Kp + (size_t)8 * 1048576;     // 4M shorts
    short* Wqkv = Vp + (size_t)4 * 1048576;     // 3M shorts (wq,wk,wv)
    short* Wob  = Wqkv + (size_t)3 * 1048576;   // 1M shorts (wo)
    short* AO   = xb;   // alias: xb consumed by QKV GEMM before flash writes AO

    convert_all<<<dim3(2048), dim3(256), 0, stream>>>(x, wq, wk, wv, wo, xb, Wqkv);
    gemm_kernel<0><<<dim3(32, 8, 3), dim3(256), 0, stream>>>(
        xb, Wqkv, bq, bk, bv, Qp, Kp, Vp, nullptr);
    fill_aug<<<dim3(32, 4), dim3(256), 0, stream>>>(harm, Qp, Kp);
    flash_kernel<<<dim3(16, 8, 4), dim3(256), 0, stream>>>(Qp, Kp, Vp, AO);
    gemm_kernel<1><<<dim3(32, 8, 1), dim3(256), 0, stream>>>(
        AO, Wob, bo, nullptr, nullptr, nullptr, nullptr, nullptr, outF);
}

// Round 5
// 192.876 us; speedup vs baseline: 1.0019x; 1.0019x over previous
//
#include <hip/hip_runtime.h>

// ManifoldAttentionLayer on MI355X — round 13 (= R12 resubmitted; R12 bench was
// an infra failure "container failed twice", no kernel signal).
// R11 post-mortem: flash dropped out of top-5 (counted-vmcnt pipeline worked);
// gemm_kernel now tops at 54us with MfmaUtil 18 / VALU 13 / HBM 13 / Occ 29 —
// all pipes idle = latency-bound. Cause: 2-buffer gemm gives each DMA only one
// ~100cy compute phase vs ~600-900cy latency, and __syncthreads drains
// vmcnt(0) every K-step (32x). Also 768 blocks at 2/CU -> 256-block tail.
// R12/R13: apply the proven R11 recipe to gemm — 3-stage LDS ring, DMA issued
// 2 tiles ahead, boundary = s_waitcnt vmcnt(4) + raw s_barrier (loads in
// flight across barriers); __launch_bounds__(256,3) so all 768 blocks
// co-resident (48KB x 3 = 144KB LDS/CU). Flash unchanged from R11.

using short8  = __attribute__((ext_vector_type(8))) short;
using short4v = __attribute__((ext_vector_type(4))) short;
using float4v = __attribute__((ext_vector_type(4))) float;

#define MFMA16(a, b, c) __builtin_amdgcn_mfma_f32_16x16x32_bf16((a), (b), (c), 0, 0, 0)

#define LOG2E 1.44269504088896f

static __device__ __forceinline__ short f2bf(float f) {
    union { float f; unsigned u; } v; v.f = f;
    unsigned r = v.u + 0x7fffu + ((v.u >> 16) & 1u);   // round-to-nearest-even
    return (short)(r >> 16);
}

// pack two f32 -> packed bf16 pair (round-half-up): 2 adds + 1 v_perm. PROVEN R5-R11.
static __device__ __forceinline__ unsigned pack2bf(float lo, float hi) {
    union { float f; unsigned u; } a, b;
    a.f = lo; b.f = hi;
    return __builtin_amdgcn_perm(b.u + 0x8000u, a.u + 0x8000u, 0x07060302u);
}

// async global->LDS DMA, 16B/lane; LDS dest = wave-uniform base + lane*16.
static __device__ __forceinline__ void dma16(const short* g, short* l) {
    __builtin_amdgcn_global_load_lds((const __attribute__((address_space(1))) void*)g,
                                     (__attribute__((address_space(3))) void*)l, 16, 0, 0);
}

// ---------------- 1) fp32 -> bf16: x and the 4 weight matrices ----------------
__global__ __launch_bounds__(256) void convert_all(
    const float* __restrict__ x,  const float* __restrict__ wq,
    const float* __restrict__ wk, const float* __restrict__ wv,
    const float* __restrict__ wo, short* __restrict__ xb, short* __restrict__ wb) {
    int idx = blockIdx.x * 256 + threadIdx.x;
    for (int i = idx; i < 2097152; i += gridDim.x * 256) {
        const float* src; short* dst;
        if (i < 1048576) {
            src = x + (size_t)i * 4;
            dst = xb + (size_t)i * 4;
        } else {
            int j = i - 1048576;
            int sel = j >> 18;
            const float* w = (sel == 0) ? wq : (sel == 1) ? wk : (sel == 2) ? wv : wo;
            src = w + (size_t)(j & 262143) * 4;
            dst = wb + (size_t)j * 4;
        }
        float4v v = *(const float4v*)src;
        short4v o;
        o.x = f2bf(v.x); o.y = f2bf(v.y); o.z = f2bf(v.z); o.w = f2bf(v.w);
        *(short4v*)dst = o;
    }
}

// ---------------- 2+4) fill augmented dims of Q'/K' (gram inline) ----------------
__global__ __launch_bounds__(256) void fill_aug(const float* __restrict__ harm,
                                                short* __restrict__ Qp,
                                                short* __restrict__ Kp) {
    int b  = blockIdx.y;
    int lc = blockIdx.x;
    int tid = threadIdx.x;
    int ll = tid >> 3;
    int d8 = (tid & 7) * 8;
    int l  = lc * 32 + ll;

    __shared__ float hs[64][33];
    for (int i = tid; i < 2048; i += 256) hs[i >> 5][i & 31] = harm[(size_t)b * 2048 + i];
    __syncthreads();

    float src = (l + 0.5f) * 0.0625f - 0.5f;
    if (src < 0.f) src = 0.f;
    int r0 = (int)floorf(src); if (r0 > 63) r0 = 63;
    int r1 = r0 + 1;           if (r1 > 63) r1 = 63;
    float wy = src - (float)r0;

    float hr[32];
    #pragma unroll
    for (int k = 0; k < 32; k++) hr[k] = (1.f - wy) * hs[r0][k] + wy * hs[r1][k];

    short8 qa, ka;
    #pragma unroll
    for (int j = 0; j < 8; j++) {
        float g = 0.f;
        #pragma unroll
        for (int k = 0; k < 32; k++) g += hr[k] * hs[d8 + j][k];
        qa[j] = f2bf(0.1f * LOG2E * g);
    }
    #pragma unroll
    for (int j = 0; j < 8; j++) {
        float vv = 0.f;
        if (d8 + j == r0) vv += 1.f - wy;
        if (d8 + j == r1) vv += wy;
        ka[j] = f2bf(vv);
    }
    for (int h = 0; h < 16; h++) {
        size_t base = (((size_t)(b * 16 + h) * 1024 + l) << 7) + 64 + d8;
        *(short8*)(Qp + base) = qa;
        *(short8*)(Kp + base) = ka;
    }
}

// ---------------- 3/6) GEMM: 3-stage ring, 2-ahead DMA, counted vmcnt ----------
template <int MODE>
__global__ __launch_bounds__(256, 3) void gemm_kernel(
    const short* __restrict__ A,
    const short* __restrict__ Wb,
    const float* __restrict__ B0, const float* __restrict__ B1, const float* __restrict__ B2,
    short* __restrict__ Qp, short* __restrict__ Kp, short* __restrict__ Vp,
    float* __restrict__ outF) {
    const int z = blockIdx.z;
    const short* W  = Wb + (size_t)z * 1048576;
    const float* Bs = (z == 0) ? B0 : ((z == 1) ? B1 : B2);

    __shared__ short Sm[3][8192];   // [buf][A 0..4096 | W 4096..8192], 48 KB

    const int tid  = threadIdx.x;
    const int lane = tid & 63;
    const int wv   = tid >> 6;
    const int wm   = (wv >> 1) * 64;
    const int wn   = (wv & 1) * 64;
    const int l16  = lane & 15;
    const int quad = lane >> 4;
    const int bm   = blockIdx.x * 128;
    const int bn   = blockIdx.y * 128;

    const short* aSrc[2];
    const short* wSrc[2];
    #pragma unroll
    for (int j = 0; j < 2; j++) {
        int c = j * 256 + tid;
        int r = c >> 2, gs = (c & 3) ^ ((r >> 1) & 3);
        aSrc[j] = A + (size_t)(bm + r) * 1024 + gs * 8;
        wSrc[j] = W + (size_t)(bn + r) * 1024 + gs * 8;
    }
    const int fr = (quad ^ ((l16 >> 1) & 3)) * 8;
    int ai[4], bi[4];
    #pragma unroll
    for (int t = 0; t < 4; t++) {
        ai[t] = (wm + t * 16 + l16) * 32 + fr;
        bi[t] = 4096 + (wn + t * 16 + l16) * 32 + fr;
    }

    float4v zero4 = {0.f, 0.f, 0.f, 0.f};
    float4v acc[4][4];
    #pragma unroll
    for (int i = 0; i < 4; i++)
        #pragma unroll
        for (int j = 0; j < 4; j++) acc[i][j] = zero4;

    // prologue: T0 -> buf0, T1 -> buf1 (8 DMAs/wave in flight), wait T0 only.
    dma16(aSrc[0], &Sm[0][wv * 512]);
    dma16(aSrc[1], &Sm[0][2048 + wv * 512]);
    dma16(wSrc[0], &Sm[0][4096 + wv * 512]);
    dma16(wSrc[1], &Sm[0][6144 + wv * 512]);
    #pragma unroll
    for (int j = 0; j < 2; j++) { aSrc[j] += 32; wSrc[j] += 32; }
    dma16(aSrc[0], &Sm[1][wv * 512]);
    dma16(aSrc[1], &Sm[1][2048 + wv * 512]);
    dma16(wSrc[0], &Sm[1][4096 + wv * 512]);
    dma16(wSrc[1], &Sm[1][6144 + wv * 512]);
    #pragma unroll
    for (int j = 0; j < 2; j++) { aSrc[j] += 32; wSrc[j] += 32; }

    asm volatile("s_waitcnt vmcnt(4)" ::: "memory");
    __builtin_amdgcn_s_barrier();
    __builtin_amdgcn_sched_barrier(0);

    int bufR = 0;   // read buffer for tile kt
    int bufW = 2;   // write buffer for tile kt+2

    for (int kt = 0; kt < 32; kt++) {
        if (kt < 30) {
            short* wbuf = &Sm[bufW][0];
            dma16(aSrc[0], wbuf + wv * 512);
            dma16(aSrc[1], wbuf + 2048 + wv * 512);
            dma16(wSrc[0], wbuf + 4096 + wv * 512);
            dma16(wSrc[1], wbuf + 6144 + wv * 512);
            #pragma unroll
            for (int j = 0; j < 2; j++) { aSrc[j] += 32; wSrc[j] += 32; }
        }

        const short* rbuf = &Sm[bufR][0];
        short8 af[4], bfr[4];
        #pragma unroll
        for (int mt = 0; mt < 4; mt++) af[mt]  = *(const short8*)&rbuf[ai[mt]];
        #pragma unroll
        for (int nt = 0; nt < 4; nt++) bfr[nt] = *(const short8*)&rbuf[bi[nt]];
        #pragma unroll
        for (int mt = 0; mt < 4; mt++)
            #pragma unroll
            for (int nt = 0; nt < 4; nt++)
                acc[mt][nt] = MFMA16(af[mt], bfr[nt], acc[mt][nt]);

        // boundary: retire tile kt+1's 4 DMAs, leave kt+2's 4 in flight.
        if (kt < 31) {
            if (kt < 30) {
                asm volatile("s_waitcnt vmcnt(4)" ::: "memory");
            } else {
                asm volatile("s_waitcnt vmcnt(0)" ::: "memory");
            }
            __builtin_amdgcn_s_barrier();
            __builtin_amdgcn_sched_barrier(0);
        }
        bufR = (bufR >= 2) ? 0 : bufR + 1;
        bufW = (bufW >= 2) ? 0 : bufW + 1;
    }

    #pragma unroll
    for (int mt = 0; mt < 4; mt++)
        #pragma unroll
        for (int nt = 0; nt < 4; nt++) {
            int col = bn + wn + nt * 16 + l16;
            float bias = Bs[col];
            #pragma unroll
            for (int r = 0; r < 4; r++) {
                int row = bm + wm + mt * 16 + quad * 4 + r;
                float val = acc[mt][nt][r] + bias;
                if (MODE == 1) {
                    outF[(size_t)row * 1024 + col] = val;
                } else {
                    int b = row >> 10, l = row & 1023;
                    int h = col >> 6,  d = col & 63;
                    size_t bhl = (size_t)(b * 16 + h) * 1024 + l;
                    if (z == 0)      Qp[(bhl << 7) + d] = f2bf(val * (0.125f * LOG2E));
                    else if (z == 1) Kp[(bhl << 7) + d] = f2bf(val);
                    else {
                        int slot = (l & ~31) | (((l >> 2) & 3) << 3) |
                                   (((l >> 4) & 1) << 2) | (l & 3);
                        Vp[(((size_t)(b * 16 + h) * 64 + d) << 10) + slot] = f2bf(val);
                    }
                }
            }
        }
}

// ---------------- 5) flash attention: 256 thr, 4 waves x 32 q, 3-buf pipeline ----
// Unchanged from R11 (passed): DMA 2 tiles ahead, boundary = vmcnt(6) + raw
// s_barrier; buffer (kt+2)%3 last read at kt-1, two barriers before rewrite.
__global__ __launch_bounds__(256, 2)
void flash_kernel(const short* __restrict__ Qp,
                  const short* __restrict__ Kp,
                  const short* __restrict__ Vp,
                  short* __restrict__ AO) {
    const int h  = blockIdx.x;
    const int qb = blockIdx.y;
    const int b  = blockIdx.z;
    const int tid  = threadIdx.x;
    const int lane = tid & 63;
    const int w    = tid >> 6;          // wave 0..3, owns 32 q rows
    const int l16  = lane & 15;
    const int quad = lane >> 4;
    const size_t bh = (size_t)(b * 16 + h);

    __shared__ short Ks[24576];   // 3 x 8192 shorts (64 key x 128 d)
    __shared__ short Vs[12288];   // 3 x 4096 shorts (64 d x 64 slot)

    // Q fragments (B-operand): u-half, lane l16 -> q row w*32+u*16+l16, k = c*32+quad*8+j
    short8 qf[2][4];
    #pragma unroll
    for (int u = 0; u < 2; u++) {
        const short* Qb = Qp + ((bh * 1024 + qb * 128 + w * 32 + u * 16 + l16) << 7) + quad * 8;
        #pragma unroll
        for (int c = 0; c < 4; c++) qf[u][c] = *(const short8*)(Qb + c * 32);
    }

    // staging sources (source-side swizzle, lane-linear LDS); wave w owns
    // keys/d-rows w*16 .. w*16+15
    const short* kSrc[4];
    #pragma unroll
    for (int jj = 0; jj < 4; jj++) {
        int key = w * 16 + jj * 4 + quad;
        kSrc[jj] = Kp + (bh << 17) + key * 128 + ((l16 ^ (key & 15)) * 8);
    }
    const short* vSrc[2];
    #pragma unroll
    for (int g = 0; g < 2; g++) {
        int d = w * 16 + g * 8 + (lane >> 3);
        vSrc[g] = Vp + (bh << 16) + d * 1024 + (((lane & 7) ^ (d & 7)) * 8);
    }

    int krd[4];
    #pragma unroll
    for (int c = 0; c < 4; c++) krd[c] = l16 * 128 + (((c * 4 + quad) ^ l16) * 8);
    int vrd[2];
    #pragma unroll
    for (int g = 0; g < 2; g++) vrd[g] = l16 * 64 + (((g * 4 + quad) ^ (l16 & 7)) * 8);

    // prologue: T0 -> buf0, T1 -> buf1 (12 DMAs/wave outstanding), then wait
    // for T0 only (vmcnt(6): in-order retirement, 6 oldest = T0's).
    #pragma unroll
    for (int jj = 0; jj < 4; jj++) dma16(kSrc[jj], &Ks[w * 2048 + jj * 512]);
    #pragma unroll
    for (int g = 0; g < 2; g++) dma16(vSrc[g], &Vs[w * 1024 + g * 512]);
    #pragma unroll
    for (int jj = 0; jj < 4; jj++) kSrc[jj] += 8192;
    #pragma unroll
    for (int g = 0; g < 2; g++) vSrc[g] += 64;
    #pragma unroll
    for (int jj = 0; jj < 4; jj++) dma16(kSrc[jj], &Ks[8192 + w * 2048 + jj * 512]);
    #pragma unroll
    for (int g = 0; g < 2; g++) dma16(vSrc[g], &Vs[4096 + w * 1024 + g * 512]);
    #pragma unroll
    for (int jj = 0; jj < 4; jj++) kSrc[jj] += 8192;
    #pragma unroll
    for (int g = 0; g < 2; g++) vSrc[g] += 64;

    float4v zero4 = {0.f, 0.f, 0.f, 0.f};
    float4v o_acc[2][4];
    #pragma unroll
    for (int u = 0; u < 2; u++)
        #pragma unroll
        for (int mt = 0; mt < 4; mt++) o_acc[u][mt] = zero4;
    float4v l_acc[2] = {zero4, zero4};

    asm volatile("s_waitcnt vmcnt(6)" ::: "memory");
    __builtin_amdgcn_s_barrier();
    __builtin_amdgcn_sched_barrier(0);

    int bufR = 0;   // read buffer for tile kt
    int bufW = 2;   // write buffer for tile kt+2

    for (int kt = 0; kt < 16; kt++) {
        if (kt < 14) {
            const int wb = bufW << 13;   // K base (shorts)
            const int wv2 = bufW << 12;  // V base
            #pragma unroll
            for (int jj = 0; jj < 4; jj++) dma16(kSrc[jj], &Ks[wb + w * 2048 + jj * 512]);
            #pragma unroll
            for (int g = 0; g < 2; g++) dma16(vSrc[g], &Vs[wv2 + w * 1024 + g * 512]);
            #pragma unroll
            for (int jj = 0; jj < 4; jj++) kSrc[jj] += 8192;
            #pragma unroll
            for (int g = 0; g < 2; g++) vSrc[g] += 64;
        }
        const int kb = bufR << 13;
        const int vb = bufR << 12;

        // S^T = K·Q^T (C-layout: col=l16=q, row=key=mt*16+quad*4+r); kf shared by u=0,1
        float4v s[2][4];
        #pragma unroll
        for (int mt = 0; mt < 4; mt++) {
            short8 kf[4];
            #pragma unroll
            for (int c = 0; c < 4; c++) kf[c] = *(const short8*)&Ks[kb + krd[c] + mt * 2048];
            #pragma unroll
            for (int u = 0; u < 2; u++) {
                s[u][mt] = MFMA16(kf[0], qf[u][0], zero4);
                #pragma unroll
                for (int c = 1; c < 4; c++)
                    s[u][mt] = MFMA16(kf[c], qf[u][c], s[u][mt]);
            }
        }

        // p = exp2(s); l accumulates as float4 (chain depth 4, not 32)
        #pragma unroll
        for (int u = 0; u < 2; u++)
            #pragma unroll
            for (int mt = 0; mt < 4; mt++) {
                #pragma unroll
                for (int r = 0; r < 4; r++)
                    s[u][mt][r] = __builtin_exp2f(s[u][mt][r]);
                #pragma unroll
                for (int r = 0; r < 4; r++)
                    l_acc[u][r] += s[u][mt][r];
            }

        // O^T += V^T · P^T; vf shared by u=0,1
        #pragma unroll
        for (int g = 0; g < 2; g++) {
            short8 pf[2];
            #pragma unroll
            for (int u = 0; u < 2; u++) {
                union { unsigned uu[4]; short8 v; } t;
                t.uu[0] = pack2bf(s[u][2 * g][0], s[u][2 * g][1]);
                t.uu[1] = pack2bf(s[u][2 * g][2], s[u][2 * g][3]);
                t.uu[2] = pack2bf(s[u][2 * g + 1][0], s[u][2 * g + 1][1]);
                t.uu[3] = pack2bf(s[u][2 * g + 1][2], s[u][2 * g + 1][3]);
                pf[u] = t.v;
            }
            #pragma unroll
            for (int mt = 0; mt < 4; mt++) {
                short8 vf = *(const short8*)&Vs[vb + vrd[g] + mt * 1024];
                #pragma unroll
                for (int u = 0; u < 2; u++)
                    o_acc[u][mt] = MFMA16(vf, pf[u], o_acc[u][mt]);
            }
        }

        // iteration boundary: wait only for tile kt+1 (leave kt+2's 6 in flight)
        if (kt < 15) {
            if (kt < 14) {
                asm volatile("s_waitcnt vmcnt(6)" ::: "memory");
            } else {
                asm volatile("s_waitcnt vmcnt(0)" ::: "memory");
            }
            __builtin_amdgcn_s_barrier();
            __builtin_amdgcn_sched_barrier(0);
        }
        bufR = (bufR >= 2) ? 0 : bufR + 1;
        bufW = (bufW >= 2) ? 0 : bufW + 1;
    }

    // epilogue: reduce l lanes + quads, normalize, store (per q-half)
    #pragma unroll
    for (int u = 0; u < 2; u++) {
        float l = l_acc[u][0] + l_acc[u][1] + l_acc[u][2] + l_acc[u][3];
        l += __shfl_xor(l, 16, 64);
        l += __shfl_xor(l, 32, 64);
        float inv = 1.0f / l;
        int row = b * 1024 + qb * 128 + w * 32 + u * 16 + l16;
        #pragma unroll
        for (int mt = 0; mt < 4; mt++) {
            short4v ov;
            #pragma unroll
            for (int r = 0; r < 4; r++) ov[r] = f2bf(o_acc[u][mt][r] * inv);
            *(short4v*)(AO + (size_t)row * 1024 + h * 64 + mt * 16 + quad * 4) = ov;
        }
    }
}

extern "C" void kernel_launch(void* const* d_in, const int* in_sizes, int n_in,
                              void* d_out, int out_size, void* d_ws, size_t ws_size,
                              hipStream_t stream) {
    const float* x    = (const float*)d_in[0];
    const float* harm = (const float*)d_in[1];
    const float* wq   = (const float*)d_in[2];
    const float* bq   = (const float*)d_in[3];
    const float* wk   = (const float*)d_in[4];
    const float* bk   = (const float*)d_in[5];
    const float* wv   = (const float*)d_in[6];
    const float* bv   = (const float*)d_in[7];
    const float* wo   = (const float*)d_in[8];
    const float* bo   = (const float*)d_in[9];
    float* outF = (float*)d_out;

    short* xb   = (short*)d_ws;                 // 4M shorts; ALIASED as AO
    short* Qp   = xb + (size_t)4 * 1048576;     // 8M shorts
    short* Kp   = Qp + (size_t)8 * 1048576;     // 8M shorts
    short* Vp   = Kp + (size_t)8 * 1048576;     // 4M shorts
    short* Wqkv = Vp + (size_t)4 * 1048576;     // 3M shorts (wq,wk,wv)
    short* Wob  = Wqkv + (size_t)3 * 1048576;   // 1M shorts (wo)
    short* AO   = xb;   // alias: xb consumed by QKV GEMM before flash writes AO

    convert_all<<<dim3(2048), dim3(256), 0, stream>>>(x, wq, wk, wv, wo, xb, Wqkv);
    gemm_kernel<0><<<dim3(32, 8, 3), dim3(256), 0, stream>>>(
        xb, Wqkv, bq, bk, bv, Qp, Kp, Vp, nullptr);
    fill_aug<<<dim3(32, 4), dim3(256), 0, stream>>>(harm, Qp, Kp);
    flash_kernel<<<dim3(16, 8, 4), dim3(256), 0, stream>>>(Qp, Kp, Vp, AO);
    gemm_kernel<1><<<dim3(32, 8, 1), dim3(256), 0, stream>>>(
        AO, Wob, bo, nullptr, nullptr, nullptr, nullptr, nullptr, outF);
}